// Round 1
// baseline (589.502 us; speedup 1.0000x reference)
//
#include <hip/hip_runtime.h>
#include <math.h>

#define N 8192
#define BIT 32
#define NCLASS 100
#define ALPHA 0.1
#define BEITA 1.0
#define GAMMA 0.1

#define TILE 128
#define LD (TILE + 4)   // pad to keep float4 alignment (multiple of 4) and cut store conflicts to ~4-way

// ws layout (bytes):
//   [0..31]    double accum[4]  {pair_tri_sum, cls_sum, m2_sum, bal_sum}
//   [64..463]  int counts[NCLASS]
//   [512..519] float scales[2]  {scale_pos, scale_neg}
//   [576.. ]   int labels[N]

// ---------------- labels + class histogram (coalesced single pass over y) -------------
__global__ void labels_kernel(const float* __restrict__ y, int* __restrict__ labels,
                              int* __restrict__ counts) {
    int idx = blockIdx.x * blockDim.x + threadIdx.x;
    if (idx >= N * NCLASS) return;
    if (y[idx] > 0.5f) {
        int row = idx / NCLASS;
        int c = idx - row * NCLASS;
        labels[row] = c;
        atomicAdd(&counts[c], 1);
    }
}

// ---------------- s0/s1 scales from histogram -------------
__global__ void scales_kernel(const int* __restrict__ counts, float* __restrict__ scales) {
    if (threadIdx.x == 0) {
        double simsum = 0.0;
        for (int c = 0; c < NCLASS; ++c) { double v = (double)counts[c]; simsum += v * v; }
        double s1 = simsum - (double)N;
        double s0 = (double)N * (double)N - simsum;
        if (s0 == 0.0) s0 = 1.0;
        if (s1 == 0.0) s1 = 1.0;
        double s = s0 + s1;
        scales[0] = (float)(s / s1);  // positive-pair scale
        scales[1] = (float)(s / s0);  // negative-pair scale
    }
}

// ---------------- pairwise hash loss: strict upper triangle, 128x128 tiles -------------
__global__ __launch_bounds__(256) void pair_kernel(const float* __restrict__ u,
                                                   const int* __restrict__ labels,
                                                   const float* __restrict__ scales,
                                                   double* __restrict__ accum) {
    const int ti = blockIdx.y, tj = blockIdx.x;
    if (tj < ti) return;                    // upper triangle of tiles only

    __shared__ float As[BIT][LD];
    __shared__ float Bs[BIT][LD];
    __shared__ int   La[TILE], Lb[TILE];
    __shared__ float wred[4];

    const int t  = threadIdx.x;
    const int i0 = ti * TILE, j0 = tj * TILE;

    // Stage u tiles k-major: As[k][r] = u[i0+r][k]. 1024 float4 chunks per side, 4 per thread.
    #pragma unroll
    for (int q = 0; q < 4; ++q) {
        int idx = t + q * 256;              // 0..1023
        int r  = idx >> 3;                  // row within tile
        int c4 = idx & 7;                   // float4 chunk within the 32-wide row
        float4 v = *(const float4*)(u + (size_t)(i0 + r) * BIT + c4 * 4);
        As[c4 * 4 + 0][r] = v.x; As[c4 * 4 + 1][r] = v.y;
        As[c4 * 4 + 2][r] = v.z; As[c4 * 4 + 3][r] = v.w;
        float4 w = *(const float4*)(u + (size_t)(j0 + r) * BIT + c4 * 4);
        Bs[c4 * 4 + 0][r] = w.x; Bs[c4 * 4 + 1][r] = w.y;
        Bs[c4 * 4 + 2][r] = w.z; Bs[c4 * 4 + 3][r] = w.w;
    }
    if (t < TILE) { La[t] = labels[i0 + t]; Lb[t] = labels[j0 + t]; }
    __syncthreads();

    const int tx = t & 15, ty = t >> 4;     // 16x16 thread grid, each owns 8x8 (split 4+4)
    float acc[8][8];
    #pragma unroll
    for (int a = 0; a < 8; ++a)
        #pragma unroll
        for (int b = 0; b < 8; ++b) acc[a][b] = 0.f;

    #pragma unroll
    for (int k = 0; k < BIT; ++k) {
        float av[8], bv[8];
        *(float4*)&av[0] = *(const float4*)&As[k][ty * 4];
        *(float4*)&av[4] = *(const float4*)&As[k][64 + ty * 4];
        *(float4*)&bv[0] = *(const float4*)&Bs[k][tx * 4];
        *(float4*)&bv[4] = *(const float4*)&Bs[k][64 + tx * 4];
        #pragma unroll
        for (int a = 0; a < 8; ++a)
            #pragma unroll
            for (int b = 0; b < 8; ++b)
                acc[a][b] = fmaf(av[a], bv[b], acc[a][b]);
    }

    const float spos = scales[0], sneg = scales[1];
    float sum = 0.f;
    #pragma unroll
    for (int a = 0; a < 8; ++a) {
        int ra = (a < 4) ? (ty * 4 + a) : (64 + ty * 4 + a - 4);
        int gi = i0 + ra;
        int la = La[ra];
        #pragma unroll
        for (int b = 0; b < 8; ++b) {
            int rb = (b < 4) ? (tx * 4 + b) : (64 + tx * 4 + b - 4);
            int gj = j0 + rb;
            if (gj <= gi) continue;         // strict upper triangle (drops diagonal too)
            float th = acc[a][b] * 0.5f;
            float sp = fmaxf(th, 0.f) + __logf(1.f + __expf(-fabsf(th)));
            bool sim = (la == Lb[rb]);
            sum += sim ? (sp - th) * spos : sp * sneg;
        }
    }

    // block reduce -> one double atomic
    #pragma unroll
    for (int o = 32; o; o >>= 1) sum += __shfl_down(sum, o, 64);
    if ((t & 63) == 0) wred[t >> 6] = sum;
    __syncthreads();
    if (t == 0) atomicAdd(&accum[0], (double)(wred[0] + wred[1] + wred[2] + wred[3]));
}

// ---------------- classification: wave-per-row log-softmax over 100 classes -------------
__global__ void cls_kernel(const float* __restrict__ Y, const int* __restrict__ labels,
                           double* __restrict__ accum) {
    const int lane = threadIdx.x & 63;
    const int wid  = blockIdx.x * (blockDim.x >> 6) + (threadIdx.x >> 6);
    float wsum = 0.f;
    #pragma unroll 1
    for (int rr = 0; rr < 16; ++rr) {
        int row = wid * 16 + rr;
        const float* p = Y + (size_t)row * NCLASS;
        float x0 = p[lane];
        float x1 = (lane < NCLASS - 64) ? p[64 + lane] : -1e30f;
        float m = fmaxf(x0, x1);
        #pragma unroll
        for (int o = 32; o; o >>= 1) m = fmaxf(m, __shfl_xor(m, o, 64));
        float e = __expf(x0 - m) + ((lane < NCLASS - 64) ? __expf(x1 - m) : 0.f);
        #pragma unroll
        for (int o = 32; o; o >>= 1) e += __shfl_xor(e, o, 64);
        if (lane == 0) wsum += m + __logf(e) - p[labels[row]];
    }
    __shared__ double bs[4];
    if (lane == 0) bs[threadIdx.x >> 6] = (double)wsum;
    __syncthreads();
    if (threadIdx.x == 0) atomicAdd(&accum[1], bs[0] + bs[1] + bs[2] + bs[3]);
}

// ---------------- quantization + balancing: one thread per row of u -------------
__global__ void quant_kernel(const float* __restrict__ u, double* __restrict__ accum) {
    const int i = blockIdx.x * blockDim.x + threadIdx.x;   // row, grid sized to N exactly
    float rs = 0.f, bal = 0.f;
    const float4* p = (const float4*)(u + (size_t)i * BIT);
    #pragma unroll
    for (int q = 0; q < 8; ++q) {
        float4 v = p[q];
        float vv[4] = {v.x, v.y, v.z, v.w};
        #pragma unroll
        for (int j = 0; j < 4; ++j) {
            float x = vv[j];
            rs += x;
            float b = (x > 0.f) ? 1.f : ((x < 0.f) ? -1.f : 0.f);  // sign(0)=0, like jnp.sign
            float d = x - b;
            bal = fmaf(d, d, bal);
        }
    }
    float m  = rs * (1.f / BIT);
    float m2 = m * m;
    #pragma unroll
    for (int o = 32; o; o >>= 1) { m2 += __shfl_down(m2, o, 64); bal += __shfl_down(bal, o, 64); }
    __shared__ double s1[4], s2[4];
    if ((threadIdx.x & 63) == 0) { s1[threadIdx.x >> 6] = (double)m2; s2[threadIdx.x >> 6] = (double)bal; }
    __syncthreads();
    if (threadIdx.x == 0) {
        atomicAdd(&accum[2], s1[0] + s1[1] + s1[2] + s1[3]);
        atomicAdd(&accum[3], s2[0] + s2[1] + s2[2] + s2[3]);
    }
}

// ---------------- finalize -------------
__global__ void fin_kernel(const double* __restrict__ accum, float* __restrict__ out) {
    if (threadIdx.x == 0 && blockIdx.x == 0) {
        double pair_full = 2.0 * accum[0];                      // symmetric matrix, diag excluded
        double lik  = pair_full / ((double)N * (double)(N - 1)); // sum / 2 / (n(n-1)/2)
        double cls  = accum[1] / (double)N;
        double quant = ALPHA * (accum[2] / (double)N);
        double bal  = GAMMA * (accum[3] / ((double)N * (double)BIT));
        out[0] = (float)(lik + BEITA * cls + quant + bal);
    }
}

extern "C" void kernel_launch(void* const* d_in, const int* in_sizes, int n_in,
                              void* d_out, int out_size, void* d_ws, size_t ws_size,
                              hipStream_t stream) {
    const float* u = (const float*)d_in[0];   // [N, BIT]
    const float* Y = (const float*)d_in[1];   // [N, NCLASS]
    const float* y = (const float*)d_in[2];   // [N, NCLASS] one-hot
    float* out = (float*)d_out;

    char* ws = (char*)d_ws;
    double* accum  = (double*)(ws + 0);
    int*    counts = (int*)(ws + 64);
    float*  scales = (float*)(ws + 512);
    int*    labels = (int*)(ws + 576);

    // zero accumulators + histogram (ws is poisoned 0xAA before every call)
    hipMemsetAsync(d_ws, 0, 512, stream);

    labels_kernel<<<(N * NCLASS + 255) / 256, 256, 0, stream>>>(y, labels, counts);
    scales_kernel<<<1, 64, 0, stream>>>(counts, scales);
    dim3 grid(N / TILE, N / TILE);
    pair_kernel<<<grid, 256, 0, stream>>>(u, labels, scales, accum);
    cls_kernel<<<N / 16 / 4, 256, 0, stream>>>(Y, labels, accum);
    quant_kernel<<<N / 256, 256, 0, stream>>>(u, accum);
    fin_kernel<<<1, 64, 0, stream>>>(accum, out);
}

// Round 2
// 135.056 us; speedup vs baseline: 4.3649x; 4.3649x over previous
//
#include <hip/hip_runtime.h>
#include <math.h>

#define N 8192
#define BIT 32
#define NCLASS 100
#define ALPHA 0.1
#define BEITA 1.0
#define GAMMA 0.1

#define BT 128            // block tile (128x128 output per block)
#define NT (N / BT)       // 64 tile-rows

typedef __attribute__((ext_vector_type(8))) short s16x8;   // 8 bf16 (4 VGPRs)
typedef __attribute__((ext_vector_type(4))) float f32x4;   // MFMA accum

// round-to-nearest-even fp32 -> bf16 bits
static __device__ __forceinline__ unsigned short f2bf(float f) {
    unsigned int x = __float_as_uint(f);
    x += 0x7fff + ((x >> 16) & 1);
    return (unsigned short)(x >> 16);
}

// ws layout (bytes):
//   [0..31]    double accum[4]  {pair_tri_sum, cls_sum, m2_sum, bal_sum}
//   [64..463]  int counts[NCLASS]
//   [512..519] float scales[2]  {scale_pos, scale_neg}
//   [576.. ]   int labels[N]

// ---------------- labels + class histogram -------------
__global__ void labels_kernel(const float* __restrict__ y, int* __restrict__ labels,
                              int* __restrict__ counts) {
    int idx = blockIdx.x * blockDim.x + threadIdx.x;
    if (idx >= N * NCLASS) return;
    if (y[idx] > 0.5f) {
        int row = idx / NCLASS;
        int c = idx - row * NCLASS;
        labels[row] = c;
        atomicAdd(&counts[c], 1);
    }
}

// ---------------- s0/s1 scales (one wave) -------------
__global__ void scales_kernel(const int* __restrict__ counts, float* __restrict__ scales) {
    int l = threadIdx.x;  // 64 threads
    double v = 0.0;
    if (l < NCLASS) { double c = (double)counts[l]; v = c * c; }
    if (l + 64 < NCLASS) { double c = (double)counts[l + 64]; v += c * c; }
    #pragma unroll
    for (int o = 32; o; o >>= 1) v += __shfl_down(v, o, 64);
    if (l == 0) {
        double s1 = v - (double)N;
        double s0 = (double)N * (double)N - v;
        if (s0 == 0.0) s0 = 1.0;
        if (s1 == 0.0) s1 = 1.0;
        double s = s0 + s1;
        scales[0] = (float)(s / s1);  // positive-pair scale
        scales[1] = (float)(s / s0);  // negative-pair scale
    }
}

// ---------------- pairwise hash loss: bf16 MFMA, triangular grid -------------
__global__ __launch_bounds__(256, 3) void pair_kernel(const float* __restrict__ u,
                                                      const int* __restrict__ labels,
                                                      const float* __restrict__ scales,
                                                      double* __restrict__ accum) {
    // decode triangular block index -> (ti, tj), ti <= tj
    int b = blockIdx.x;
    int ti = 0;
    while (b >= NT - ti) { b -= NT - ti; ++ti; }
    const int tj = ti + b;
    const int i0 = ti * BT, j0 = tj * BT;

    // [kchunk][stagedrow][8 bf16]: frag reads AND staging stores are contiguous-16B -> conflict-free
    __shared__ __align__(16) unsigned short Us[4][256][8];   // 16 KB
    __shared__ int Ls[256];
    __shared__ float wred[4];

    const int t = threadIdx.x;

    // stage: thread t owns staged row t (rows 0..127 = A rows i0.., 128..255 = B rows j0..)
    {
        const int g = (t < BT) ? (i0 + t) : (j0 + t - BT);
        const float4* p = (const float4*)(u + (size_t)g * BIT);
        #pragma unroll
        for (int c = 0; c < 4; ++c) {
            float4 v0 = p[2 * c], v1 = p[2 * c + 1];
            s16x8 fr;
            fr[0] = (short)f2bf(v0.x); fr[1] = (short)f2bf(v0.y);
            fr[2] = (short)f2bf(v0.z); fr[3] = (short)f2bf(v0.w);
            fr[4] = (short)f2bf(v1.x); fr[5] = (short)f2bf(v1.y);
            fr[6] = (short)f2bf(v1.z); fr[7] = (short)f2bf(v1.w);
            *(s16x8*)&Us[c][t][0] = fr;
        }
        Ls[t] = labels[g];
    }
    __syncthreads();

    const int w = t >> 6;                 // wave 0..3, 2x2 wave grid, 64x64 per wave
    const int wy = w >> 1, wx = w & 1;
    const int lane = t & 63;
    const int quad = lane >> 4, lr = lane & 15;

    // A-frag lane l: A[m=lr][k=quad*8+j] = u[i0+row][quad*8+j]  (contiguous 8 bf16)
    // B-frag lane l: B[k=quad*8+j][n=lr] = u[j0+row][quad*8+j]  (same gather)
    s16x8 av[4], bv[4];
    #pragma unroll
    for (int x = 0; x < 4; ++x) {
        av[x] = *(const s16x8*)&Us[quad][wy * 64 + x * 16 + lr][0];
        bv[x] = *(const s16x8*)&Us[quad][128 + wx * 64 + x * 16 + lr][0];
    }

    f32x4 acc[4][4];
    #pragma unroll
    for (int a = 0; a < 4; ++a)
        #pragma unroll
        for (int c = 0; c < 4; ++c)
            acc[a][c] = __builtin_amdgcn_mfma_f32_16x16x32_bf16(
                av[a], bv[c], (f32x4){0.f, 0.f, 0.f, 0.f}, 0, 0, 0);

    // epilogue: softplus + scale, strict upper triangle (diag masked via sc=0)
    const float spos = scales[0], sneg = scales[1];
    int lbv[4], lav[16];
    #pragma unroll
    for (int c = 0; c < 4; ++c) lbv[c] = Ls[128 + wx * 64 + c * 16 + lr];
    #pragma unroll
    for (int a = 0; a < 4; ++a)
        #pragma unroll
        for (int r = 0; r < 4; ++r) lav[a * 4 + r] = Ls[wy * 64 + a * 16 + quad * 4 + r];

    float sum = 0.f;
    #pragma unroll
    for (int a = 0; a < 4; ++a) {
        #pragma unroll
        for (int r = 0; r < 4; ++r) {
            const int gi = i0 + wy * 64 + a * 16 + quad * 4 + r;
            const int la = lav[a * 4 + r];
            #pragma unroll
            for (int c = 0; c < 4; ++c) {
                const int gj = j0 + wx * 64 + c * 16 + lr;
                float th = 0.5f * acc[a][c][r];       // C/D: col=lane&15, row=quad*4+reg
                float e = __expf(-fabsf(th));
                float lg = __logf(1.f + e);
                bool sim = (la == lbv[c]);
                // sim: (sp - th) = softplus(-th); !sim: sp = softplus(th)
                float base = sim ? fmaxf(-th, 0.f) : fmaxf(th, 0.f);
                float sc = sim ? spos : sneg;
                sc = (gj > gi) ? sc : 0.f;
                sum = fmaf(base + lg, sc, sum);
            }
        }
    }

    #pragma unroll
    for (int o = 32; o; o >>= 1) sum += __shfl_down(sum, o, 64);
    if (lane == 0) wred[w] = sum;
    __syncthreads();
    if (t == 0) atomicAdd(&accum[0], (double)(wred[0] + wred[1] + wred[2] + wred[3]));
}

// ---------------- classification: wave-per-4-rows log-softmax over 100 classes -------------
__global__ void cls_kernel(const float* __restrict__ Y, const int* __restrict__ labels,
                           double* __restrict__ accum) {
    const int lane = threadIdx.x & 63;
    const int wid  = blockIdx.x * (blockDim.x >> 6) + (threadIdx.x >> 6);
    float wsum = 0.f;
    #pragma unroll 1
    for (int rr = 0; rr < 4; ++rr) {
        int row = wid * 4 + rr;
        const float* p = Y + (size_t)row * NCLASS;
        float x0 = p[lane];
        float x1 = (lane < NCLASS - 64) ? p[64 + lane] : -1e30f;
        float m = fmaxf(x0, x1);
        #pragma unroll
        for (int o = 32; o; o >>= 1) m = fmaxf(m, __shfl_xor(m, o, 64));
        float e = __expf(x0 - m) + ((lane < NCLASS - 64) ? __expf(x1 - m) : 0.f);
        #pragma unroll
        for (int o = 32; o; o >>= 1) e += __shfl_xor(e, o, 64);
        if (lane == 0) wsum += m + __logf(e) - p[labels[row]];
    }
    __shared__ double bs[4];
    if (lane == 0) bs[threadIdx.x >> 6] = (double)wsum;
    __syncthreads();
    if (threadIdx.x == 0) atomicAdd(&accum[1], bs[0] + bs[1] + bs[2] + bs[3]);
}

// ---------------- quantization + balancing: one thread per row of u -------------
__global__ void quant_kernel(const float* __restrict__ u, double* __restrict__ accum) {
    const int i = blockIdx.x * blockDim.x + threadIdx.x;
    float rs = 0.f, bal = 0.f;
    const float4* p = (const float4*)(u + (size_t)i * BIT);
    #pragma unroll
    for (int q = 0; q < 8; ++q) {
        float4 v = p[q];
        float vv[4] = {v.x, v.y, v.z, v.w};
        #pragma unroll
        for (int j = 0; j < 4; ++j) {
            float x = vv[j];
            rs += x;
            float bb = (x > 0.f) ? 1.f : ((x < 0.f) ? -1.f : 0.f);
            float d = x - bb;
            bal = fmaf(d, d, bal);
        }
    }
    float m  = rs * (1.f / BIT);
    float m2 = m * m;
    #pragma unroll
    for (int o = 32; o; o >>= 1) { m2 += __shfl_down(m2, o, 64); bal += __shfl_down(bal, o, 64); }
    __shared__ double s1[4], s2[4];
    if ((threadIdx.x & 63) == 0) { s1[threadIdx.x >> 6] = (double)m2; s2[threadIdx.x >> 6] = (double)bal; }
    __syncthreads();
    if (threadIdx.x == 0) {
        atomicAdd(&accum[2], s1[0] + s1[1] + s1[2] + s1[3]);
        atomicAdd(&accum[3], s2[0] + s2[1] + s2[2] + s2[3]);
    }
}

// ---------------- finalize -------------
__global__ void fin_kernel(const double* __restrict__ accum, float* __restrict__ out) {
    if (threadIdx.x == 0 && blockIdx.x == 0) {
        double pair_full = 2.0 * accum[0];                       // symmetric, diag excluded
        double lik   = pair_full / ((double)N * (double)(N - 1));
        double cls   = accum[1] / (double)N;
        double quant = ALPHA * (accum[2] / (double)N);
        double bal   = GAMMA * (accum[3] / ((double)N * (double)BIT));
        out[0] = (float)(lik + BEITA * cls + quant + bal);
    }
}

extern "C" void kernel_launch(void* const* d_in, const int* in_sizes, int n_in,
                              void* d_out, int out_size, void* d_ws, size_t ws_size,
                              hipStream_t stream) {
    const float* u = (const float*)d_in[0];   // [N, BIT]
    const float* Y = (const float*)d_in[1];   // [N, NCLASS]
    const float* y = (const float*)d_in[2];   // [N, NCLASS] one-hot
    float* out = (float*)d_out;

    char* ws = (char*)d_ws;
    double* accum  = (double*)(ws + 0);
    int*    counts = (int*)(ws + 64);
    float*  scales = (float*)(ws + 512);
    int*    labels = (int*)(ws + 576);

    hipMemsetAsync(d_ws, 0, 512, stream);

    labels_kernel<<<(N * NCLASS + 255) / 256, 256, 0, stream>>>(y, labels, counts);
    scales_kernel<<<1, 64, 0, stream>>>(counts, scales);
    pair_kernel<<<NT * (NT + 1) / 2, 256, 0, stream>>>(u, labels, scales, accum);
    cls_kernel<<<N / 4 / 4, 256, 0, stream>>>(Y, labels, accum);
    quant_kernel<<<N / 256, 256, 0, stream>>>(u, accum);
    fin_kernel<<<1, 64, 0, stream>>>(accum, out);
}